// Round 2
// baseline (254.191 us; speedup 1.0000x reference)
//
#include <hip/hip_runtime.h>
#include <hip/hip_bf16.h>

#define KE_F  332.0636f
#define MAX_M 1024   // padded molecule count (harness M = 1000)
#define BLK   256
#define NBLK  1024   // 4 blocks/CU x 256 CUs exact fill at __launch_bounds__(256,4)

typedef int   ivec4 __attribute__((ext_vector_type(4)));
typedef float fvec4 __attribute__((ext_vector_type(4)));

__device__ __forceinline__ float softplusf(float x) {
    return logf(1.0f + expf(x));
}

// One block: prefix-scan num_atoms -> mol_starts[M+1]; derived constants into
// params: [0..3]=c_k/sum(c), [4..7]=exponents_k/d, [16..111]=Z^zexp table;
// also zeroes out[0..M) (harness re-poisons d_out to 0xAA each launch).
__global__ void scan_params_kernel(const int* __restrict__ num_atoms, int M,
                                   const float* __restrict__ d_inv,
                                   const float* __restrict__ z_exp_inv,
                                   const float* __restrict__ c_inv,
                                   const float* __restrict__ exp_inv,
                                   int* __restrict__ mol_starts,
                                   float* __restrict__ params,
                                   float* __restrict__ out) {
    __shared__ int buf[MAX_M];
    int t = threadIdx.x;
    buf[t] = (t < M) ? num_atoms[t] : 0;
    __syncthreads();
    for (int off = 1; off < MAX_M; off <<= 1) {   // Hillis-Steele inclusive scan
        int x = (t >= off) ? buf[t - off] : 0;
        __syncthreads();
        buf[t] += x;
        __syncthreads();
    }
    if (t == 0) mol_starts[0] = 0;
    if (t < M) mol_starts[t + 1] = buf[t];
    if (t == 0) {
        float dd = softplusf(d_inv[0]);
        float c0 = softplusf(c_inv[0]), c1 = softplusf(c_inv[1]);
        float c2 = softplusf(c_inv[2]), c3 = softplusf(c_inv[3]);
        float e0 = softplusf(exp_inv[0]), e1 = softplusf(exp_inv[1]);
        float e2 = softplusf(exp_inv[2]), e3 = softplusf(exp_inv[3]);
        float ic = 1.0f / (c0 + c1 + c2 + c3);
        float id = 1.0f / dd;
        params[0] = c0 * ic; params[1] = c1 * ic; params[2] = c2 * ic; params[3] = c3 * ic;
        params[4] = e0 * id; params[5] = e1 * id; params[6] = e2 * id; params[7] = e3 * id;
    }
    if (t < 96) {                                  // z in [1,94): table of Z^zexp
        float zexp = softplusf(z_exp_inv[0]);
        params[16 + t] = __powf((float)t, zexp);
    }
    for (int k = t; k < M; k += MAX_M) out[k] = 0.0f;
}

// Per-atom packing: pack[a] = (x, y, z, encode(mol, Z)) where
// encode = float((mol << 7) | Z)  (exact: < 2^17). mol via binary search on
// mol_starts (clamps to M-1, matching jnp.repeat total_repeat_length pad).
__global__ void pack_kernel(const float* __restrict__ xyz,
                            const int* __restrict__ z,
                            const int* __restrict__ mol_starts, int M, int N,
                            float4* __restrict__ pack) {
    int a = blockIdx.x * blockDim.x + threadIdx.x;
    if (a >= N) return;
    int lo = 0, hi = M;
    while (hi - lo > 1) {
        int mid = (lo + hi) >> 1;
        if (mol_starts[mid] <= a) lo = mid; else hi = mid;
    }
    pack[a] = make_float4(xyz[3 * a + 0], xyz[3 * a + 1], xyz[3 * a + 2],
                          (float)((lo << 7) | z[a]));
}

// Depth-2 software pipeline. Previous version issued the 8 divergent pack[]
// gathers immediately before use -> per-iteration serial chain
// (stream load ~600cy -> addr -> gathers ~300cy -> math); VALUBusy 19%,
// nothing saturated. Here: while math runs on batch X, gathers for batch
// X+1 and the streaming edge loads for batch X+2 are already in flight.
// Trip count is grid-uniform (clamped indices; validity folded into the
// per-edge mask) so the pipeline body has no divergent control flow.
__global__ __launch_bounds__(BLK, 4) void nr_main_kernel(
    const int* __restrict__ nbrs, const float* __restrict__ offsets,
    const float4* __restrict__ pack,
    const float* __restrict__ params, float* __restrict__ out, int E, int M) {
    __shared__ float sm[MAX_M];
    __shared__ float zp[96];
    for (int t = threadIdx.x; t < MAX_M; t += BLK) sm[t] = 0.0f;
    if (threadIdx.x < 96) zp[threadIdx.x] = params[16 + threadIdx.x];
    __syncthreads();

    const float4 kk = *(const float4*)(params + 0);   // phi coefficients
    const float4 gg = *(const float4*)(params + 4);   // exponent scales (/d folded)

    const int ngroups = E >> 2;                       // 4 edges per group
    const int stride  = gridDim.x * BLK;
    const ivec4* nb4 = (const ivec4*)nbrs;
    const fvec4* of4 = (const fvec4*)offsets;

// Streaming edge load (coalesced, nontemporal; index clamped so OOB threads
// issue harmless redundant loads instead of diverging).
#define LOAD_S(g, N01, N23, O0, O1, O2) do {                                  \
        const size_t _c = (size_t)((g) < ngroups ? (g) : ngroups - 1);        \
        N01 = __builtin_nontemporal_load(nb4 + 2 * _c);                       \
        N23 = __builtin_nontemporal_load(nb4 + 2 * _c + 1);                   \
        O0  = __builtin_nontemporal_load(of4 + 3 * _c);                       \
        O1  = __builtin_nontemporal_load(of4 + 3 * _c + 1);                   \
        O2  = __builtin_nontemporal_load(of4 + 3 * _c + 2);                   \
    } while (0)

// Issue all 8 gathers for one 4-edge batch; masked lanes broadcast pack[0]
// (coalesces to one line). Validity folded into the mask bits. Offset
// components copied out so the stream regs can be reused for prefetch.
#define ISSUE_G(g, N01, N23, O0, O1, O2, MB, PI, PJ, OX, OY, OZ) do {         \
        const bool _v = (g) < ngroups;                                        \
        const int _i0 = N01.x, _i1 = N01.z, _i2 = N23.x, _i3 = N23.z;         \
        const int _j0 = N01.y, _j1 = N01.w, _j2 = N23.y, _j3 = N23.w;         \
        const bool _m0 = _v && (_j0 > _i0), _m1 = _v && (_j1 > _i1);          \
        const bool _m2 = _v && (_j2 > _i2), _m3 = _v && (_j3 > _i3);          \
        MB = (int)_m0 | ((int)_m1 << 1) | ((int)_m2 << 2) | ((int)_m3 << 3);  \
        PI[0] = pack[_m0 ? _i0 : 0]; PJ[0] = pack[_m0 ? _j0 : 0];             \
        PI[1] = pack[_m1 ? _i1 : 0]; PJ[1] = pack[_m1 ? _j1 : 0];             \
        PI[2] = pack[_m2 ? _i2 : 0]; PJ[2] = pack[_m2 ? _j2 : 0];             \
        PI[3] = pack[_m3 ? _i3 : 0]; PJ[3] = pack[_m3 ? _j3 : 0];             \
        OX[0] = O0.x; OX[1] = O0.w; OX[2] = O1.z; OX[3] = O2.y;               \
        OY[0] = O0.y; OY[1] = O1.x; OY[2] = O1.w; OY[3] = O2.z;               \
        OZ[0] = O0.z; OZ[1] = O1.y; OZ[2] = O2.x; OZ[3] = O2.w;               \
    } while (0)

// Per-edge math, identical arithmetic to the verified baseline (absmax 0.0).
#define MATH_G(MB, PI, PJ, OX, OY, OZ) do {                                   \
        _Pragma("unroll")                                                     \
        for (int k = 0; k < 4; ++k) {                                         \
            const float dx = PI[k].x - PJ[k].x - OX[k];                       \
            const float dy = PI[k].y - PJ[k].y - OY[k];                       \
            const float dz = PI[k].z - PJ[k].z - OZ[k];                       \
            const float r2 = fmaf(dx, dx, fmaf(dy, dy, dz * dz)) + 3e-15f;    \
            const bool ok = (((MB) >> k) & 1) && (r2 < 25.0f);                \
            const int  wi = (int)PI[k].w;                                     \
            const int  wj = (int)PJ[k].w;                                     \
            const float zi = (float)(wi & 127);                               \
            const float zj = (float)(wj & 127);                               \
            const float inv_r = rsqrtf(r2);                                   \
            const float r = r2 * inv_r;                                       \
            const float S = zp[wi & 127] + zp[wj & 127];                      \
            const float rs = r * S;                                           \
            const float phi = kk.x * __expf(-gg.x * rs) + kk.y * __expf(-gg.y * rs) + \
                              kk.z * __expf(-gg.z * rs) + kk.w * __expf(-gg.w * rs);  \
            const float fc = __expf(-__fdividef(r2, 25.0f - r2));             \
            const float val = KE_F * zi * zj * inv_r * phi * fc;              \
            if (ok) atomicAdd(&sm[wi >> 7], val);                             \
        }                                                                     \
    } while (0)

    if (ngroups > 0) {
        const int ITER = (ngroups + stride - 1) / stride;   // grid-uniform (=8)
        int gA = blockIdx.x * BLK + threadIdx.x;
        int gB = gA + stride;

        ivec4 aN01, aN23; fvec4 aO0, aO1, aO2;              // A stream regs
        ivec4 bN01, bN23; fvec4 bO0, bO1, bO2;              // B stream regs
        float4 api[4], apj[4], bpi[4], bpj[4];
        float  aox[4], aoy[4], aoz[4], box[4], boy[4], boz[4];
        int    amb, bmb;

        // prologue: streams for A and B in flight, gathers for A in flight
        LOAD_S(gA, aN01, aN23, aO0, aO1, aO2);
        LOAD_S(gB, bN01, bN23, bO0, bO1, bO2);
        ISSUE_G(gA, aN01, aN23, aO0, aO1, aO2, amb, api, apj, aox, aoy, aoz);

        for (int it = 0; ; it += 2) {
            const int gC = gA + 2 * stride;
            const int gD = gB + 2 * stride;
            const bool more = (it + 2 < ITER);              // uniform branch
            // B gathers (B stream arrived one math-phase ago)
            ISSUE_G(gB, bN01, bN23, bO0, bO1, bO2, bmb, bpi, bpj, box, boy, boz);
            // prefetch stream for gC into freed A stream regs
            if (more) LOAD_S(gC, aN01, aN23, aO0, aO1, aO2);
            // math on A (its gathers have been in flight for a full phase)
            MATH_G(amb, api, apj, aox, aoy, aoz);
            if (more) {
                // gathers for gC (stream latency covered by MATH_G above)
                ISSUE_G(gC, aN01, aN23, aO0, aO1, aO2, amb, api, apj, aox, aoy, aoz);
                // prefetch stream for gD into freed B stream regs
                LOAD_S(gD, bN01, bN23, bO0, bO1, bO2);
            }
            MATH_G(bmb, bpi, bpj, box, boy, boz);
            if (!more) break;
            gA = gC; gB = gD;
        }
    }
#undef LOAD_S
#undef ISSUE_G
#undef MATH_G

    // Tail edges [4*ngroups, E) — scalar path (E%4, empty in harness).
    for (int e = (ngroups << 2) + blockIdx.x * BLK + threadIdx.x; e < E; e += stride) {
        const int i = nbrs[2 * e], j = nbrs[2 * e + 1];
        if (j <= i) continue;
        const float oxs = offsets[3 * e], oys = offsets[3 * e + 1], ozs = offsets[3 * e + 2];
        const float4 pis = pack[i], pjs = pack[j];
        const float dx = pis.x - pjs.x - oxs;
        const float dy = pis.y - pjs.y - oys;
        const float dz = pis.z - pjs.z - ozs;
        const float r2 = fmaf(dx, dx, fmaf(dy, dy, dz * dz)) + 3e-15f;
        if (r2 >= 25.0f) continue;
        const int  wi = (int)pis.w;
        const int  wj = (int)pjs.w;
        const float inv_r = rsqrtf(r2);
        const float r = r2 * inv_r;
        const float S = zp[wi & 127] + zp[wj & 127];
        const float rs = r * S;
        const float phi = kk.x * __expf(-gg.x * rs) + kk.y * __expf(-gg.y * rs) +
                          kk.z * __expf(-gg.z * rs) + kk.w * __expf(-gg.w * rs);
        const float fc = __expf(-__fdividef(r2, 25.0f - r2));
        atomicAdd(&sm[wi >> 7],
                  KE_F * (float)(wi & 127) * (float)(wj & 127) * inv_r * phi * fc);
    }

    __syncthreads();
    // Sparse flush: ~35% of slots nonzero per block; NBLK=1024 halves the
    // global-atomic count vs the 2048-block baseline (~0.35M total).
    for (int t = threadIdx.x; t < M; t += BLK) {
        const float v = sm[t];
        if (v != 0.0f) atomicAdd(&out[t], v);
    }
}

extern "C" void kernel_launch(void* const* d_in, const int* in_sizes, int n_in,
                              void* d_out, int out_size, void* d_ws, size_t ws_size,
                              hipStream_t stream) {
    const float* xyz       = (const float*)d_in[0];
    const int*   z         = (const int*)d_in[1];
    const int*   nbrs      = (const int*)d_in[2];
    const int*   num_atoms = (const int*)d_in[3];
    const float* offsets   = (const float*)d_in[4];
    const float* d_inv     = (const float*)d_in[5];
    const float* z_exp_inv = (const float*)d_in[6];
    const float* c_inv     = (const float*)d_in[7];
    const float* exp_inv   = (const float*)d_in[8];
    float* out = (float*)d_out;

    const int N = in_sizes[0] / 3;
    const int E = in_sizes[2] / 2;
    const int M = in_sizes[3];

    // Workspace layout (16B-aligned regions):
    //   [0, 4096)            : mol_starts (M+1 ints)
    //   [4096, 8192)         : params (112 floats used)
    //   [8192, 8192+16N)     : pack (N float4; w = (mol<<7)|Z encoded)
    char* w = (char*)d_ws;
    int*    mol_starts = (int*)w;
    float*  params     = (float*)(w + 4096);
    float4* pack       = (float4*)(w + 8192);

    scan_params_kernel<<<1, MAX_M, 0, stream>>>(num_atoms, M, d_inv, z_exp_inv,
                                                c_inv, exp_inv, mol_starts,
                                                params, out);
    pack_kernel<<<(N + BLK - 1) / BLK, BLK, 0, stream>>>(xyz, z, mol_starts, M, N,
                                                         pack);
    nr_main_kernel<<<NBLK, BLK, 0, stream>>>(nbrs, offsets, pack,
                                             params, out, E, M);
}